// Round 9
// baseline (70.489 us; speedup 1.0000x reference)
//
#include <hip/hip_runtime.h>

// B=2, S=2048, D_MODEL=1024, H=16, E=64.  Inputs/outputs FLOAT32.
// out = Q (norm * K^T V)  -- reassociated, no S x S scores.
// convert_pack -> qkv_gemm (256x256, K_STEP=64, k-half-sectioned double
// buffer, 4-phase counted-vmcnt(4) pipeline, wave-uniform consumption,
// transposed epilogue) -> kv_outer (MFMA) -> qm_out (fused reduce + Q.M).

typedef __attribute__((ext_vector_type(8))) __bf16 bf16x8;
typedef __attribute__((ext_vector_type(8))) short short8;
typedef __attribute__((ext_vector_type(4))) float f32x4;
typedef __attribute__((ext_vector_type(4))) unsigned short ushort4v;

#define NX  4194304   // 4096*1024
#define NW1 1048576   // 1024*1024
#define NW  3145728   // 3*NW1

__device__ __forceinline__ float bf2f(unsigned short u) {
  union { unsigned int i; float f; } v; v.i = ((unsigned int)u) << 16; return v.f;
}
__device__ __forceinline__ unsigned short f2bf(float f) {
  union { float f; unsigned int i; } v; v.f = f;
  unsigned int u = v.i;
  u += 0x7fffu + ((u >> 16) & 1u);   // RNE
  return (unsigned short)(u >> 16);
}

__device__ __forceinline__ void gload_lds16(const void* g, void* l) {
  __builtin_amdgcn_global_load_lds(
      (const __attribute__((address_space(1))) void*)(unsigned long long)(g),
      (__attribute__((address_space(3))) void*)(unsigned int)(unsigned long long)(l),
      16, 0, 0);
}

// ---------------------------------------------------------------------------
// Kernel 0: f32 -> bf16 convert/pack.
// ---------------------------------------------------------------------------
__global__ __launch_bounds__(256) void convert_pack(
    const float* __restrict__ x,
    const float* __restrict__ wq, const float* __restrict__ wk,
    const float* __restrict__ wv,
    const float* __restrict__ bq, const float* __restrict__ bk,
    const float* __restrict__ bv,
    unsigned short* __restrict__ Xbf, unsigned short* __restrict__ Wcat,
    float* __restrict__ Bcat)
{
  const long long t8 = ((long long)blockIdx.x * 256 + threadIdx.x) * 8;
  const float* src;
  unsigned short* dst;
  long long off;
  if (t8 < NX) {
    src = x; dst = Xbf; off = t8;
  } else if (t8 < NX + NW) {
    const long long w = t8 - NX;
    const int z = (int)(w >> 20);
    off = w & (NW1 - 1);
    src = (z == 0) ? wq : (z == 1) ? wk : wv;
    dst = Wcat + (long long)z * NW1;
  } else if (t8 < NX + NW + 3072) {
    const long long bo = t8 - (NX + NW);
    const int z = (int)(bo >> 10);
    const long long o2 = bo & 1023;
    const float* bsrc = (z == 0) ? bq : (z == 1) ? bk : bv;
    *(f32x4*)(Bcat + z * 1024 + o2)     = *(const f32x4*)(bsrc + o2);
    *(f32x4*)(Bcat + z * 1024 + o2 + 4) = *(const f32x4*)(bsrc + o2 + 4);
    return;
  } else {
    return;
  }
  f32x4 v0 = *(const f32x4*)(src + off);
  f32x4 v1 = *(const f32x4*)(src + off + 4);
  union { short8 s; unsigned short u[8]; } o;
#pragma unroll
  for (int j = 0; j < 4; ++j) {
    o.u[j]     = f2bf(v0[j]);
    o.u[4 + j] = f2bf(v1[j]);
  }
  *(short8*)(dst + off) = o.s;
}

// ---------------------------------------------------------------------------
// Kernel 1: C[r,c] = sum_d Xbf[r,d]*Wcat[c,d] + Bcat[c].
// R=4096, C=3072, K=1024.  BM=BN=256, K_STEP=64, 8 waves (2M x 4N, wave
// tile 128x64), grid 16x12 = 192.  LDS: 2 K-step buffers x 4 sections
// {Ak0,Ak1,Bk0,Bk1}, each [256 rows][32 k] bf16 (16 KiB, 64-B rows ->
// conflict-free ds_read_b128, no swizzle).  K-HALF sectioning makes
// consumption wave-uniform.  Per K-step t, 4 phases:
//   P1: vmcnt(4); barrier; read A-ks0 frags (8) + B-ks0 n0-1 (2);
//       stage Ak0(t+1); 16 MFMA (n0-1, ks0)
//   P2: read B-ks0 n2-3 (2); stage Bk0(t+1); 16 MFMA (n2-3, ks0)
//   P3: vmcnt(4); barrier; read A-ks1 (8) + B-ks1 n0-1; stage Ak1(t+1);
//       16 MFMA (n0-1, ks1)
//   P4: read B-ks1 n2-3; stage Bk1(t+1); 16 MFMA (n2-3, ks1)
// Ledger: P1 needs Ak0,Bk0(t) staged 4,3 phases earlier -> vmcnt(4) exact;
// P3 symmetric.  Never <4 outstanding until peeled final step.
// Epilogue: transposed per-head stores Qt/Kt/Vt[bh][64][2048], 8B packed.
// ---------------------------------------------------------------------------
__global__ __launch_bounds__(512, 1) void qkv_gemm(
    const unsigned short* __restrict__ Xbf,
    const unsigned short* __restrict__ Wcat,
    const float* __restrict__ Bcat,
    unsigned short* __restrict__ Qt,
    unsigned short* __restrict__ Kt,
    unsigned short* __restrict__ Vt)
{
  __shared__ unsigned char lds[131072];     // 2 bufs x 4 sections x 16 KiB

  const int tid = threadIdx.x;
  int bid = blockIdx.x;
  bid = (bid & 7) * 24 + (bid >> 3);        // bijective XCD swizzle (192%8==0)
  const int colBase = (bid % 12) * 256;     // 12 col tiles
  const int rowBase = (bid / 12) * 256;     // 16 row tiles

  const int lane = tid & 63;
  const int wid  = tid >> 6;                // 0..7
  const int wr = (wid >> 2) * 128;          // 2 M-waves, 128 rows each
  const int wc = (wid & 3) * 64;            // 4 N-waves, 64 cols each
  const int lr = lane & 15;
  const int lk = lane >> 4;

  // staging: section = 1024 16B units; thread covers units tid, tid+512.
  // unit i: row = i>>2, kcol8 = i&3.  src2 = src1 + 128 rows.
  const size_t aoff = (size_t)(rowBase + (tid >> 2)) * 1024 + (tid & 3) * 8;
  const size_t boff = (size_t)(colBase + (tid >> 2)) * 1024 + (tid & 3) * 8;
  const int d1 = tid * 16, d2 = 8192 + tid * 16;

#define STG(secl, gsrc)                                   \
  { gload_lds16((gsrc),               (secl) + d1);       \
    gload_lds16((gsrc) + 128 * 1024,  (secl) + d2); }

  f32x4 acc[8][4] = {};

  // prologue: K-step 0 sections in consumption-critical order
  STG(lds + 0,     Xbf  + aoff + 0);     // Ak0(0)
  STG(lds + 32768, Wcat + boff + 0);     // Bk0(0)
  STG(lds + 16384, Xbf  + aoff + 32);    // Ak1(0)
  STG(lds + 49152, Wcat + boff + 32);    // Bk1(0)

  const int frA = (wr + lr) * 64 + lk * 16;   // + m*1024 per frag row-step
  const int frB = (wc + lr) * 64 + lk * 16;

  for (int t = 0; t < 16; ++t) {
    const unsigned char* bufc = lds + (t & 1) * 65536;
    unsigned char* bufn = lds + ((t + 1) & 1) * 65536;
    const size_t kno = (size_t)(t + 1) * 64;   // next K-step global k offset
    const bool st = (t < 15);

    bf16x8 a0, a1, a2, a3, a4, a5, a6, a7, b0, b1;

    // ---- P1: (ks0, n0-1) ----
    asm volatile("s_waitcnt vmcnt(4)" ::: "memory");
    __builtin_amdgcn_s_barrier();
    {
      const unsigned char* As = bufc;          // Ak0
      const unsigned char* Bs = bufc + 32768;  // Bk0
      a0 = *(const bf16x8*)(As + frA);
      a1 = *(const bf16x8*)(As + frA + 1024);
      a2 = *(const bf16x8*)(As + frA + 2048);
      a3 = *(const bf16x8*)(As + frA + 3072);
      a4 = *(const bf16x8*)(As + frA + 4096);
      a5 = *(const bf16x8*)(As + frA + 5120);
      a6 = *(const bf16x8*)(As + frA + 6144);
      a7 = *(const bf16x8*)(As + frA + 7168);
      b0 = *(const bf16x8*)(Bs + frB);
      b1 = *(const bf16x8*)(Bs + frB + 1024);
      if (st) STG(bufn + 0, Xbf + aoff + kno);            // Ak0(t+1)
      __builtin_amdgcn_s_setprio(1);
      acc[0][0] = __builtin_amdgcn_mfma_f32_16x16x32_bf16(a0, b0, acc[0][0], 0, 0, 0);
      acc[1][0] = __builtin_amdgcn_mfma_f32_16x16x32_bf16(a1, b0, acc[1][0], 0, 0, 0);
      acc[2][0] = __builtin_amdgcn_mfma_f32_16x16x32_bf16(a2, b0, acc[2][0], 0, 0, 0);
      acc[3][0] = __builtin_amdgcn_mfma_f32_16x16x32_bf16(a3, b0, acc[3][0], 0, 0, 0);
      acc[4][0] = __builtin_amdgcn_mfma_f32_16x16x32_bf16(a4, b0, acc[4][0], 0, 0, 0);
      acc[5][0] = __builtin_amdgcn_mfma_f32_16x16x32_bf16(a5, b0, acc[5][0], 0, 0, 0);
      acc[6][0] = __builtin_amdgcn_mfma_f32_16x16x32_bf16(a6, b0, acc[6][0], 0, 0, 0);
      acc[7][0] = __builtin_amdgcn_mfma_f32_16x16x32_bf16(a7, b0, acc[7][0], 0, 0, 0);
      acc[0][1] = __builtin_amdgcn_mfma_f32_16x16x32_bf16(a0, b1, acc[0][1], 0, 0, 0);
      acc[1][1] = __builtin_amdgcn_mfma_f32_16x16x32_bf16(a1, b1, acc[1][1], 0, 0, 0);
      acc[2][1] = __builtin_amdgcn_mfma_f32_16x16x32_bf16(a2, b1, acc[2][1], 0, 0, 0);
      acc[3][1] = __builtin_amdgcn_mfma_f32_16x16x32_bf16(a3, b1, acc[3][1], 0, 0, 0);
      acc[4][1] = __builtin_amdgcn_mfma_f32_16x16x32_bf16(a4, b1, acc[4][1], 0, 0, 0);
      acc[5][1] = __builtin_amdgcn_mfma_f32_16x16x32_bf16(a5, b1, acc[5][1], 0, 0, 0);
      acc[6][1] = __builtin_amdgcn_mfma_f32_16x16x32_bf16(a6, b1, acc[6][1], 0, 0, 0);
      acc[7][1] = __builtin_amdgcn_mfma_f32_16x16x32_bf16(a7, b1, acc[7][1], 0, 0, 0);
      __builtin_amdgcn_s_setprio(0);
      // ---- P2: (ks0, n2-3) ----
      b0 = *(const bf16x8*)(Bs + frB + 2048);
      b1 = *(const bf16x8*)(Bs + frB + 3072);
      if (st) STG(bufn + 32768, Wcat + boff + kno);       // Bk0(t+1)
      __builtin_amdgcn_s_setprio(1);
      acc[0][2] = __builtin_amdgcn_mfma_f32_16x16x32_bf16(a0, b0, acc[0][2], 0, 0, 0);
      acc[1][2] = __builtin_amdgcn_mfma_f32_16x16x32_bf16(a1, b0, acc[1][2], 0, 0, 0);
      acc[2][2] = __builtin_amdgcn_mfma_f32_16x16x32_bf16(a2, b0, acc[2][2], 0, 0, 0);
      acc[3][2] = __builtin_amdgcn_mfma_f32_16x16x32_bf16(a3, b0, acc[3][2], 0, 0, 0);
      acc[4][2] = __builtin_amdgcn_mfma_f32_16x16x32_bf16(a4, b0, acc[4][2], 0, 0, 0);
      acc[5][2] = __builtin_amdgcn_mfma_f32_16x16x32_bf16(a5, b0, acc[5][2], 0, 0, 0);
      acc[6][2] = __builtin_amdgcn_mfma_f32_16x16x32_bf16(a6, b0, acc[6][2], 0, 0, 0);
      acc[7][2] = __builtin_amdgcn_mfma_f32_16x16x32_bf16(a7, b0, acc[7][2], 0, 0, 0);
      acc[0][3] = __builtin_amdgcn_mfma_f32_16x16x32_bf16(a0, b1, acc[0][3], 0, 0, 0);
      acc[1][3] = __builtin_amdgcn_mfma_f32_16x16x32_bf16(a1, b1, acc[1][3], 0, 0, 0);
      acc[2][3] = __builtin_amdgcn_mfma_f32_16x16x32_bf16(a2, b1, acc[2][3], 0, 0, 0);
      acc[3][3] = __builtin_amdgcn_mfma_f32_16x16x32_bf16(a3, b1, acc[3][3], 0, 0, 0);
      acc[4][3] = __builtin_amdgcn_mfma_f32_16x16x32_bf16(a4, b1, acc[4][3], 0, 0, 0);
      acc[5][3] = __builtin_amdgcn_mfma_f32_16x16x32_bf16(a5, b1, acc[5][3], 0, 0, 0);
      acc[6][3] = __builtin_amdgcn_mfma_f32_16x16x32_bf16(a6, b1, acc[6][3], 0, 0, 0);
      acc[7][3] = __builtin_amdgcn_mfma_f32_16x16x32_bf16(a7, b1, acc[7][3], 0, 0, 0);
      __builtin_amdgcn_s_setprio(0);
    }
    // ---- P3: (ks1, n0-1) ----
    if (t < 15) asm volatile("s_waitcnt vmcnt(4)" ::: "memory");
    else        asm volatile("s_waitcnt vmcnt(0)" ::: "memory");
    __builtin_amdgcn_s_barrier();
    {
      const unsigned char* As = bufc + 16384;  // Ak1
      const unsigned char* Bs = bufc + 49152;  // Bk1
      a0 = *(const bf16x8*)(As + frA);
      a1 = *(const bf16x8*)(As + frA + 1024);
      a2 = *(const bf16x8*)(As + frA + 2048);
      a3 = *(const bf16x8*)(As + frA + 3072);
      a4 = *(const bf16x8*)(As + frA + 4096);
      a5 = *(const bf16x8*)(As + frA + 5120);
      a6 = *(const bf16x8*)(As + frA + 6144);
      a7 = *(const bf16x8*)(As + frA + 7168);
      b0 = *(const bf16x8*)(Bs + frB);
      b1 = *(const bf16x8*)(Bs + frB + 1024);
      if (st) STG(bufn + 16384, Xbf + aoff + kno + 32);   // Ak1(t+1)
      __builtin_amdgcn_s_setprio(1);
      acc[0][0] = __builtin_amdgcn_mfma_f32_16x16x32_bf16(a0, b0, acc[0][0], 0, 0, 0);
      acc[1][0] = __builtin_amdgcn_mfma_f32_16x16x32_bf16(a1, b0, acc[1][0], 0, 0, 0);
      acc[2][0] = __builtin_amdgcn_mfma_f32_16x16x32_bf16(a2, b0, acc[2][0], 0, 0, 0);
      acc[3][0] = __builtin_amdgcn_mfma_f32_16x16x32_bf16(a3, b0, acc[3][0], 0, 0, 0);
      acc[4][0] = __builtin_amdgcn_mfma_f32_16x16x32_bf16(a4, b0, acc[4][0], 0, 0, 0);
      acc[5][0] = __builtin_amdgcn_mfma_f32_16x16x32_bf16(a5, b0, acc[5][0], 0, 0, 0);
      acc[6][0] = __builtin_amdgcn_mfma_f32_16x16x32_bf16(a6, b0, acc[6][0], 0, 0, 0);
      acc[7][0] = __builtin_amdgcn_mfma_f32_16x16x32_bf16(a7, b0, acc[7][0], 0, 0, 0);
      acc[0][1] = __builtin_amdgcn_mfma_f32_16x16x32_bf16(a0, b1, acc[0][1], 0, 0, 0);
      acc[1][1] = __builtin_amdgcn_mfma_f32_16x16x32_bf16(a1, b1, acc[1][1], 0, 0, 0);
      acc[2][1] = __builtin_amdgcn_mfma_f32_16x16x32_bf16(a2, b1, acc[2][1], 0, 0, 0);
      acc[3][1] = __builtin_amdgcn_mfma_f32_16x16x32_bf16(a3, b1, acc[3][1], 0, 0, 0);
      acc[4][1] = __builtin_amdgcn_mfma_f32_16x16x32_bf16(a4, b1, acc[4][1], 0, 0, 0);
      acc[5][1] = __builtin_amdgcn_mfma_f32_16x16x32_bf16(a5, b1, acc[5][1], 0, 0, 0);
      acc[6][1] = __builtin_amdgcn_mfma_f32_16x16x32_bf16(a6, b1, acc[6][1], 0, 0, 0);
      acc[7][1] = __builtin_amdgcn_mfma_f32_16x16x32_bf16(a7, b1, acc[7][1], 0, 0, 0);
      __builtin_amdgcn_s_setprio(0);
      // ---- P4: (ks1, n2-3) ----
      b0 = *(const bf16x8*)(Bs + frB + 2048);
      b1 = *(const bf16x8*)(Bs + frB + 3072);
      if (st) STG(bufn + 49152, Wcat + boff + kno + 32);  // Bk1(t+1)
      __builtin_amdgcn_s_setprio(1);
      acc[0][2] = __builtin_amdgcn_mfma_f32_16x16x32_bf16(a0, b0, acc[0][2], 0, 0, 0);
      acc[1][2] = __builtin_amdgcn_mfma_f32_16x16x32_bf16(a1, b0, acc[1][2], 0, 0, 0);
      acc[2][2] = __builtin_amdgcn_mfma_f32_16x16x32_bf16(a2, b0, acc[2][2], 0, 0, 0);
      acc[3][2] = __builtin_amdgcn_mfma_f32_16x16x32_bf16(a3, b0, acc[3][2], 0, 0, 0);
      acc[4][2] = __builtin_amdgcn_mfma_f32_16x16x32_bf16(a4, b0, acc[4][2], 0, 0, 0);
      acc[5][2] = __builtin_amdgcn_mfma_f32_16x16x32_bf16(a5, b0, acc[5][2], 0, 0, 0);
      acc[6][2] = __builtin_amdgcn_mfma_f32_16x16x32_bf16(a6, b0, acc[6][2], 0, 0, 0);
      acc[7][2] = __builtin_amdgcn_mfma_f32_16x16x32_bf16(a7, b0, acc[7][2], 0, 0, 0);
      acc[0][3] = __builtin_amdgcn_mfma_f32_16x16x32_bf16(a0, b1, acc[0][3], 0, 0, 0);
      acc[1][3] = __builtin_amdgcn_mfma_f32_16x16x32_bf16(a1, b1, acc[1][3], 0, 0, 0);
      acc[2][3] = __builtin_amdgcn_mfma_f32_16x16x32_bf16(a2, b1, acc[2][3], 0, 0, 0);
      acc[3][3] = __builtin_amdgcn_mfma_f32_16x16x32_bf16(a3, b1, acc[3][3], 0, 0, 0);
      acc[4][3] = __builtin_amdgcn_mfma_f32_16x16x32_bf16(a4, b1, acc[4][3], 0, 0, 0);
      acc[5][3] = __builtin_amdgcn_mfma_f32_16x16x32_bf16(a5, b1, acc[5][3], 0, 0, 0);
      acc[6][3] = __builtin_amdgcn_mfma_f32_16x16x32_bf16(a6, b1, acc[6][3], 0, 0, 0);
      acc[7][3] = __builtin_amdgcn_mfma_f32_16x16x32_bf16(a7, b1, acc[7][3], 0, 0, 0);
      __builtin_amdgcn_s_setprio(0);
    }
  }
#undef STG

  // Epilogue.  D mapping: col = lane&15 (lr), row = lk*4 + jj.
  const int bB = rowBase >> 11;             // batch (256 | 2048)
#pragma unroll
  for (int n = 0; n < 4; ++n) {
    const int colG = colBase + wc + n * 16 + lr;
    const float bval = Bcat[colG];
    const int zone = colG >> 10;            // uniform per block (256 | 1024)
    unsigned short* __restrict__ T = (zone == 0) ? Qt : (zone == 1) ? Kt : Vt;
    const int hf = (colG >> 6) & 15;
    const int f  = colG & 63;
    const size_t rowOff = ((size_t)(bB * 16 + hf) * 64 + f) * 2048;
#pragma unroll
    for (int m = 0; m < 8; ++m) {
      const int tpos = (rowBase + wr + m * 16 + lk * 4) & 2047;
      ushort4v pk;
#pragma unroll
      for (int jj = 0; jj < 4; ++jj)
        pk[jj] = f2bf(acc[m][n][jj] + bval);
      *(ushort4v*)&T[rowOff + tpos] = pk;
    }
  }
}

// ---------------------------------------------------------------------------
// Kernel 2 (MFMA): Mpart[blk][f][e] = sum_{t in chunk} Kt[bh][f][t]*Vt[bh][e][t]
// grid 256 blocks x 64 threads (1 wave).  blk = bh*8 + tchunk.
// ---------------------------------------------------------------------------
__global__ __launch_bounds__(64) void kv_outer(
    const unsigned short* __restrict__ Kt,
    const unsigned short* __restrict__ Vt,
    float* __restrict__ Mpart)
{
  const int lane = threadIdx.x;
  const int blk = blockIdx.x;
  const int bh = blk >> 3, tc = blk & 7;
  const int lr = lane & 15, lk = lane >> 4;
  const size_t base = (size_t)bh * 64 * 2048;

  f32x4 acc[4][4] = {};
#pragma unroll
  for (int ks = 0; ks < 8; ++ks) {
    const int t0 = tc * 256 + ks * 32 + lk * 8;
    bf16x8 af[4], bf[4];
#pragma unroll
    for (int m = 0; m < 4; ++m)
      af[m] = *(const bf16x8*)&Kt[base + (size_t)(m * 16 + lr) * 2048 + t0];
#pragma unroll
    for (int n = 0; n < 4; ++n)
      bf[n] = *(const bf16x8*)&Vt[base + (size_t)(n * 16 + lr) * 2048 + t0];
#pragma unroll
    for (int m = 0; m < 4; ++m)
#pragma unroll
      for (int n = 0; n < 4; ++n)
        acc[m][n] = __builtin_amdgcn_mfma_f32_16x16x32_bf16(af[m], bf[n], acc[m][n], 0, 0, 0);
  }
  float* out = Mpart + (size_t)blk * 4096;
#pragma unroll
  for (int m = 0; m < 4; ++m)
#pragma unroll
    for (int n = 0; n < 4; ++n)
#pragma unroll
      for (int j = 0; j < 4; ++j)
        out[(m * 16 + lk * 4 + j) * 64 + n * 16 + lr] = acc[m][n][j];
}

// ---------------------------------------------------------------------------
// Kernel 3: Out[s, h*64+e] = sum_f Qt[bh][f][s] * (norm * sum_ch Mpart)[f][e]
// Fused 8-partial reduce + Q.M.  grid (16 s-chunks, 16 h, 2 b), 256 thr.
// ---------------------------------------------------------------------------
__global__ __launch_bounds__(256) void qm_out(
    const unsigned short* __restrict__ Qt, const float* __restrict__ Mpart,
    float* __restrict__ Out)
{
  __shared__ float Ms[64 * 64];      // 16 KB
  __shared__ float Qst[64 * 132];    // [f][s] padded
  const int tid = threadIdx.x;
  const int b = blockIdx.z, h = blockIdx.y, s0 = blockIdx.x * 128;
  const int bh = b * 16 + h;

#pragma unroll
  for (int i = 0; i < 4; ++i) {
    const int off = i * 1024 + tid * 4;
    f32x4 s = {};
#pragma unroll
    for (int ch = 0; ch < 8; ++ch)
      s += *(const f32x4*)&Mpart[((size_t)bh * 8 + ch) * 4096 + off];
    s *= 0.125f;   // 64^-0.5
    *(f32x4*)&Ms[off] = s;
  }
  const size_t qbase = (size_t)bh * 64 * 2048;
#pragma unroll
  for (int i = 0; i < 4; ++i) {
    const int slot = i * 256 + tid;          // 0..1023
    const int f = slot >> 4, c = slot & 15;
    short8 q = *(const short8*)&Qt[qbase + (size_t)f * 2048 + s0 + c * 8];
#pragma unroll
    for (int j = 0; j < 8; ++j)
      Qst[f * 132 + c * 8 + j] = bf2f((unsigned short)q[j]);
  }
  __syncthreads();

  const int s = (tid >> 3) * 4;       // 4 rows / thread
  const int e0 = (tid & 7) * 8;       // 8 cols / thread
  float acc2[4][8] = {};
  for (int f = 0; f < 64; ++f) {
    f32x4 m0 = *(const f32x4*)&Ms[f * 64 + e0];
    f32x4 m1 = *(const f32x4*)&Ms[f * 64 + e0 + 4];
#pragma unroll
    for (int i = 0; i < 4; ++i) {
      const float q = Qst[f * 132 + s + i];
#pragma unroll
      for (int j = 0; j < 4; ++j) {
        acc2[i][j]     += q * m0[j];
        acc2[i][j + 4] += q * m1[j];
      }
    }
  }
  const size_t obase = ((size_t)b * 2048 + s0) * 1024 + h * 64;
#pragma unroll
  for (int i = 0; i < 4; ++i) {
    f32x4 o0 = { acc2[i][0], acc2[i][1], acc2[i][2], acc2[i][3] };
    f32x4 o1 = { acc2[i][4], acc2[i][5], acc2[i][6], acc2[i][7] };
    *(f32x4*)&Out[obase + (size_t)(s + i) * 1024 + e0]     = o0;
    *(f32x4*)&Out[obase + (size_t)(s + i) * 1024 + e0 + 4] = o1;
  }
}

extern "C" void kernel_launch(void* const* d_in, const int* in_sizes, int n_in,
                              void* d_out, int out_size, void* d_ws, size_t ws_size,
                              hipStream_t stream) {
  const float* x  = (const float*)d_in[0];
  const float* Wq = (const float*)d_in[1];
  const float* Wk = (const float*)d_in[2];
  const float* Wv = (const float*)d_in[3];
  const float* bq = (const float*)d_in[4];
  const float* bk = (const float*)d_in[5];
  const float* bv = (const float*)d_in[6];
  float* out = (float*)d_out;

  char* ws = (char*)d_ws;
  const size_t MiB = 1024ull * 1024ull;
  unsigned short* Xbf   = (unsigned short*)(ws);              //  8 MiB
  unsigned short* Wcat  = (unsigned short*)(ws + 8  * MiB);   //  6 MiB
  float*          Bcat  = (float*)         (ws + 14 * MiB);   // 12 KiB
  unsigned short* Qt    = (unsigned short*)(ws + 15 * MiB);   //  8 MiB
  unsigned short* Kt    = (unsigned short*)(ws + 23 * MiB);   //  8 MiB
  unsigned short* Vt    = (unsigned short*)(ws + 31 * MiB);   //  8 MiB
  float*          Mpart = (float*)         (ws + 39 * MiB);   //  4 MiB

  convert_pack<<<3586, 256, 0, stream>>>(x, Wq, Wk, Wv, bq, bk, bv,
                                         Xbf, Wcat, Bcat);
  qkv_gemm<<<192, 512, 0, stream>>>(Xbf, Wcat, Bcat, Qt, Kt, Vt);
  kv_outer<<<256, 64, 0, stream>>>(Kt, Vt, Mpart);
  qm_out<<<dim3(16, 16, 2), 256, 0, stream>>>(Qt, Mpart, out);
}

// Round 10
// 66.311 us; speedup vs baseline: 1.0630x; 1.0630x over previous
//
#include <hip/hip_runtime.h>

// B=2, S=2048, D_MODEL=1024, H=16, E=64.  Inputs/outputs FLOAT32.
// out = Q (norm * K^T V)  -- reassociated, no S x S scores.
// convert_pack -> qkv_gemm (256x192, K_STEP=64, k-half-sectioned double
// buffer, 4-phase counted-vmcnt pipeline, XOR chunk swizzle, wave-split
// staging, transposed epilogue) -> kv_outer (MFMA) -> qm_out.

typedef __attribute__((ext_vector_type(8))) __bf16 bf16x8;
typedef __attribute__((ext_vector_type(8))) short short8;
typedef __attribute__((ext_vector_type(4))) float f32x4;
typedef __attribute__((ext_vector_type(4))) unsigned short ushort4v;

#define NX  4194304   // 4096*1024
#define NW1 1048576   // 1024*1024
#define NW  3145728   // 3*NW1

__device__ __forceinline__ float bf2f(unsigned short u) {
  union { unsigned int i; float f; } v; v.i = ((unsigned int)u) << 16; return v.f;
}
__device__ __forceinline__ unsigned short f2bf(float f) {
  union { float f; unsigned int i; } v; v.f = f;
  unsigned int u = v.i;
  u += 0x7fffu + ((u >> 16) & 1u);   // RNE
  return (unsigned short)(u >> 16);
}

__device__ __forceinline__ void gload_lds16(const void* g, void* l) {
  __builtin_amdgcn_global_load_lds(
      (const __attribute__((address_space(1))) void*)(unsigned long long)(g),
      (__attribute__((address_space(3))) void*)(unsigned int)(unsigned long long)(l),
      16, 0, 0);
}

// ---------------------------------------------------------------------------
// Kernel 0: f32 -> bf16 convert/pack.
// ---------------------------------------------------------------------------
__global__ __launch_bounds__(256) void convert_pack(
    const float* __restrict__ x,
    const float* __restrict__ wq, const float* __restrict__ wk,
    const float* __restrict__ wv,
    const float* __restrict__ bq, const float* __restrict__ bk,
    const float* __restrict__ bv,
    unsigned short* __restrict__ Xbf, unsigned short* __restrict__ Wcat,
    float* __restrict__ Bcat)
{
  const long long t8 = ((long long)blockIdx.x * 256 + threadIdx.x) * 8;
  const float* src;
  unsigned short* dst;
  long long off;
  if (t8 < NX) {
    src = x; dst = Xbf; off = t8;
  } else if (t8 < NX + NW) {
    const long long w = t8 - NX;
    const int z = (int)(w >> 20);
    off = w & (NW1 - 1);
    src = (z == 0) ? wq : (z == 1) ? wk : wv;
    dst = Wcat + (long long)z * NW1;
  } else if (t8 < NX + NW + 3072) {
    const long long bo = t8 - (NX + NW);
    const int z = (int)(bo >> 10);
    const long long o2 = bo & 1023;
    const float* bsrc = (z == 0) ? bq : (z == 1) ? bk : bv;
    *(f32x4*)(Bcat + z * 1024 + o2)     = *(const f32x4*)(bsrc + o2);
    *(f32x4*)(Bcat + z * 1024 + o2 + 4) = *(const f32x4*)(bsrc + o2 + 4);
    return;
  } else {
    return;
  }
  f32x4 v0 = *(const f32x4*)(src + off);
  f32x4 v1 = *(const f32x4*)(src + off + 4);
  union { short8 s; unsigned short u[8]; } o;
#pragma unroll
  for (int j = 0; j < 4; ++j) {
    o.u[j]     = f2bf(v0[j]);
    o.u[4 + j] = f2bf(v1[j]);
  }
  *(short8*)(dst + off) = o.s;
}

// ---------------------------------------------------------------------------
// Kernel 1: C[r,c] = sum_d Xbf[r,d]*Wcat[c,d] + Bcat[c].
// R=4096, C=3072, K=1024.  BM=256 x BN=192, K_STEP=64, 8 waves (2M x 4N,
// wave tile 128x48), grid 16x16 = 256 (1 block/CU, bijective XCD swizzle).
// LDS: 2 K-step buffers x sections {Ak0@0, Ak1@16K, Bk0@32K, Bk1@44K},
// rows 64 B, 16-B chunks XOR-swizzled by (row>>1)&3 (R6-8 verified
// conflict-free; pre-swizzled global source + same XOR on frag reads).
// Staging wave-split: waves 0-3 stage A (4 loads/k-half), waves 4-7 B (3).
// Per K-step t: P1 vmcnt(A4/B3)+barrier, read Ak0 frags + B n0-1, stage
// Ak0(t+1) [A-waves], 16 MFMA; P2 read B n2, stage Bk0(t+1) [B-waves],
// 8 MFMA; P3/P4 mirror on k-half 1.  Ledger: each wait leaves exactly the
// younger k-half's loads in flight; drains to 0 only at t=15/P3.
// Epilogue: transposed per-head stores Qt/Kt/Vt[bh][64][2048], 8B packed.
// ---------------------------------------------------------------------------
#define BUF_B 57344           // Ak0 16K + Ak1 16K + Bk0 12K + Bk1 12K
__global__ __launch_bounds__(512, 1) void qkv_gemm(
    const unsigned short* __restrict__ Xbf,
    const unsigned short* __restrict__ Wcat,
    const float* __restrict__ Bcat,
    unsigned short* __restrict__ Qt,
    unsigned short* __restrict__ Kt,
    unsigned short* __restrict__ Vt)
{
  __shared__ unsigned char lds[2 * BUF_B];   // 112 KB

  const int tid = threadIdx.x;
  int bid = blockIdx.x;
  bid = (bid & 7) * 32 + (bid >> 3);        // bijective XCD swizzle (256%8==0)
  const int colBase = (bid & 15) * 192;     // 16 col tiles
  const int rowBase = (bid >> 4) * 256;     // 16 row tiles

  const int lane = tid & 63;
  const int wid  = tid >> 6;                // 0..7
  const int wr = (wid >> 2) * 128;          // 2 M-waves, 128 rows
  const int wc = (wid & 3) * 48;            // 4 N-waves, 48 cols
  const int lr = lane & 15;
  const int lk = lane >> 4;
  const int fofs = (lk ^ ((lr >> 1) & 3)) << 4;   // swizzled frag chunk
  const int frA = (wr + lr) * 64 + fofs;    // + m*1024
  const int frB = (wc + lr) * 64 + fofs;    // + n*1024

  const bool isA = (tid < 256);
  const int nl = isA ? 4 : 3;
  const int tloc = tid & 255;

  // staging: section unit u = l*256 + tloc; row = u>>2; chunk = u&3;
  // source chunk = (u&3) ^ ((row>>1)&3)  (inverse swizzle on global addr)
  const unsigned short* gp[4];
  int dofs[4];
#pragma unroll
  for (int l = 0; l < 4; ++l) {
    const int u = l * 256 + tloc;
    const int row = u >> 2;
    const int rowc = (!isA && row > 191) ? 0 : row;
    const int csrc = (u & 3) ^ ((rowc >> 1) & 3);
    gp[l] = isA ? (Xbf  + (size_t)(rowBase + rowc) * 1024 + csrc * 8)
                : (Wcat + (size_t)(colBase + rowc) * 1024 + csrc * 8);
    dofs[l] = u * 16;
  }

#define STGRP(secbase, kofs)                                 \
  { _Pragma("unroll") for (int l = 0; l < 4; ++l)            \
      if (l < nl) gload_lds16(gp[l] + (kofs), (secbase) + dofs[l]); }

  f32x4 acc[8][3] = {};

  // prologue: K-step 0, both k-halves.  A-waves: Ak0 then Ak1; B: Bk0, Bk1.
  if (isA) { STGRP(lds + 0,     0); STGRP(lds + 16384, 32); }
  else     { STGRP(lds + 32768, 0); STGRP(lds + 45056, 32); }

  for (int t = 0; t < 16; ++t) {
    const unsigned char* bufc = lds + (t & 1) * BUF_B;
    unsigned char* bufn = lds + ((t + 1) & 1) * BUF_B;
    const size_t kno = (size_t)(t + 1) * 64;
    const bool st = (t < 15);
    bf16x8 a[8], b0, b1, b2;

    // ---- P1: k-half 0, n0-1 ----
    if (isA) asm volatile("s_waitcnt vmcnt(4)" ::: "memory");
    else     asm volatile("s_waitcnt vmcnt(3)" ::: "memory");
    __builtin_amdgcn_s_barrier();
    {
      const unsigned char* As = bufc;           // Ak0
      const unsigned char* Bs = bufc + 32768;   // Bk0
#pragma unroll
      for (int m = 0; m < 8; ++m)
        a[m] = *(const bf16x8*)(As + frA + m * 1024);
      b0 = *(const bf16x8*)(Bs + frB);
      b1 = *(const bf16x8*)(Bs + frB + 1024);
      if (st && isA) STGRP(bufn + 0, kno);      // Ak0(t+1)
      __builtin_amdgcn_s_setprio(1);
#pragma unroll
      for (int m = 0; m < 8; ++m)
        acc[m][0] = __builtin_amdgcn_mfma_f32_16x16x32_bf16(a[m], b0, acc[m][0], 0, 0, 0);
#pragma unroll
      for (int m = 0; m < 8; ++m)
        acc[m][1] = __builtin_amdgcn_mfma_f32_16x16x32_bf16(a[m], b1, acc[m][1], 0, 0, 0);
      __builtin_amdgcn_s_setprio(0);
      // ---- P2: k-half 0, n2 ----
      b2 = *(const bf16x8*)(Bs + frB + 2048);
      if (st && !isA) STGRP(bufn + 32768, kno); // Bk0(t+1)
      __builtin_amdgcn_s_setprio(1);
#pragma unroll
      for (int m = 0; m < 8; ++m)
        acc[m][2] = __builtin_amdgcn_mfma_f32_16x16x32_bf16(a[m], b2, acc[m][2], 0, 0, 0);
      __builtin_amdgcn_s_setprio(0);
    }
    // ---- P3: k-half 1, n0-1 ----
    if (st) {
      if (isA) asm volatile("s_waitcnt vmcnt(4)" ::: "memory");
      else     asm volatile("s_waitcnt vmcnt(3)" ::: "memory");
    } else {
      asm volatile("s_waitcnt vmcnt(0)" ::: "memory");
    }
    __builtin_amdgcn_s_barrier();
    {
      const unsigned char* As = bufc + 16384;   // Ak1
      const unsigned char* Bs = bufc + 45056;   // Bk1
#pragma unroll
      for (int m = 0; m < 8; ++m)
        a[m] = *(const bf16x8*)(As + frA + m * 1024);
      b0 = *(const bf16x8*)(Bs + frB);
      b1 = *(const bf16x8*)(Bs + frB + 1024);
      if (st && isA) STGRP(bufn + 16384, kno + 32);   // Ak1(t+1)
      __builtin_amdgcn_s_setprio(1);
#pragma unroll
      for (int m = 0; m < 8; ++m)
        acc[m][0] = __builtin_amdgcn_mfma_f32_16x16x32_bf16(a[m], b0, acc[m][0], 0, 0, 0);
#pragma unroll
      for (int m = 0; m < 8; ++m)
        acc[m][1] = __builtin_amdgcn_mfma_f32_16x16x32_bf16(a[m], b1, acc[m][1], 0, 0, 0);
      __builtin_amdgcn_s_setprio(0);
      // ---- P4: k-half 1, n2 ----
      b2 = *(const bf16x8*)(Bs + frB + 2048);
      if (st && !isA) STGRP(bufn + 45056, kno + 32);  // Bk1(t+1)
      __builtin_amdgcn_s_setprio(1);
#pragma unroll
      for (int m = 0; m < 8; ++m)
        acc[m][2] = __builtin_amdgcn_mfma_f32_16x16x32_bf16(a[m], b2, acc[m][2], 0, 0, 0);
      __builtin_amdgcn_s_setprio(0);
    }
  }
#undef STGRP

  // Epilogue.  D mapping: col = lane&15 (lr), row = lk*4 + jj.
  const int bB = rowBase >> 11;             // batch
#pragma unroll
  for (int n = 0; n < 3; ++n) {
    const int colG = colBase + wc + n * 16 + lr;
    const float bval = Bcat[colG];
    const int zone = colG >> 10;            // uniform per 16-col fragment
    unsigned short* __restrict__ T = (zone == 0) ? Qt : (zone == 1) ? Kt : Vt;
    const int hf = (colG >> 6) & 15;
    const int f  = colG & 63;
    const size_t rowOff = ((size_t)(bB * 16 + hf) * 64 + f) * 2048;
#pragma unroll
    for (int m = 0; m < 8; ++m) {
      const int tpos = (rowBase + wr + m * 16 + lk * 4) & 2047;
      ushort4v pk;
#pragma unroll
      for (int jj = 0; jj < 4; ++jj)
        pk[jj] = f2bf(acc[m][n][jj] + bval);
      *(ushort4v*)&T[rowOff + tpos] = pk;
    }
  }
}

// ---------------------------------------------------------------------------
// Kernel 2 (MFMA): Mpart[blk][f][e] = sum_{t in chunk} Kt[bh][f][t]*Vt[bh][e][t]
// grid 256 blocks x 64 threads (1 wave).  blk = bh*8 + tchunk.
// ---------------------------------------------------------------------------
__global__ __launch_bounds__(64) void kv_outer(
    const unsigned short* __restrict__ Kt,
    const unsigned short* __restrict__ Vt,
    float* __restrict__ Mpart)
{
  const int lane = threadIdx.x;
  const int blk = blockIdx.x;
  const int bh = blk >> 3, tc = blk & 7;
  const int lr = lane & 15, lk = lane >> 4;
  const size_t base = (size_t)bh * 64 * 2048;

  f32x4 acc[4][4] = {};
#pragma unroll
  for (int ks = 0; ks < 8; ++ks) {
    const int t0 = tc * 256 + ks * 32 + lk * 8;
    bf16x8 af[4], bf[4];
#pragma unroll
    for (int m = 0; m < 4; ++m)
      af[m] = *(const bf16x8*)&Kt[base + (size_t)(m * 16 + lr) * 2048 + t0];
#pragma unroll
    for (int n = 0; n < 4; ++n)
      bf[n] = *(const bf16x8*)&Vt[base + (size_t)(n * 16 + lr) * 2048 + t0];
#pragma unroll
    for (int m = 0; m < 4; ++m)
#pragma unroll
      for (int n = 0; n < 4; ++n)
        acc[m][n] = __builtin_amdgcn_mfma_f32_16x16x32_bf16(af[m], bf[n], acc[m][n], 0, 0, 0);
  }
  float* out = Mpart + (size_t)blk * 4096;
#pragma unroll
  for (int m = 0; m < 4; ++m)
#pragma unroll
    for (int n = 0; n < 4; ++n)
#pragma unroll
      for (int j = 0; j < 4; ++j)
        out[(m * 16 + lk * 4 + j) * 64 + n * 16 + lr] = acc[m][n][j];
}

// ---------------------------------------------------------------------------
// Kernel 3: Out[s, h*64+e] = sum_f Qt[bh][f][s] * (norm * sum_ch Mpart)[f][e]
// Fused 8-partial reduce + Q.M.  grid (16 s-chunks, 16 h, 2 b), 256 thr.
// ---------------------------------------------------------------------------
__global__ __launch_bounds__(256) void qm_out(
    const unsigned short* __restrict__ Qt, const float* __restrict__ Mpart,
    float* __restrict__ Out)
{
  __shared__ float Ms[64 * 64];      // 16 KB
  __shared__ float Qst[64 * 132];    // [f][s] padded
  const int tid = threadIdx.x;
  const int b = blockIdx.z, h = blockIdx.y, s0 = blockIdx.x * 128;
  const int bh = b * 16 + h;

#pragma unroll
  for (int i = 0; i < 4; ++i) {
    const int off = i * 1024 + tid * 4;
    f32x4 s = {};
#pragma unroll
    for (int ch = 0; ch < 8; ++ch)
      s += *(const f32x4*)&Mpart[((size_t)bh * 8 + ch) * 4096 + off];
    s *= 0.125f;   // 64^-0.5
    *(f32x4*)&Ms[off] = s;
  }
  const size_t qbase = (size_t)bh * 64 * 2048;
#pragma unroll
  for (int i = 0; i < 4; ++i) {
    const int slot = i * 256 + tid;          // 0..1023
    const int f = slot >> 4, c = slot & 15;
    short8 q = *(const short8*)&Qt[qbase + (size_t)f * 2048 + s0 + c * 8];
#pragma unroll
    for (int j = 0; j < 8; ++j)
      Qst[f * 132 + c * 8 + j] = bf2f((unsigned short)q[j]);
  }
  __syncthreads();

  const int s = (tid >> 3) * 4;       // 4 rows / thread
  const int e0 = (tid & 7) * 8;       // 8 cols / thread
  float acc2[4][8] = {};
  for (int f = 0; f < 64; ++f) {
    f32x4 m0 = *(const f32x4*)&Ms[f * 64 + e0];
    f32x4 m1 = *(const f32x4*)&Ms[f * 64 + e0 + 4];
#pragma unroll
    for (int i = 0; i < 4; ++i) {
      const float q = Qst[f * 132 + s + i];
#pragma unroll
      for (int j = 0; j < 4; ++j) {
        acc2[i][j]     += q * m0[j];
        acc2[i][j + 4] += q * m1[j];
      }
    }
  }
  const size_t obase = ((size_t)b * 2048 + s0) * 1024 + h * 64;
#pragma unroll
  for (int i = 0; i < 4; ++i) {
    f32x4 o0 = { acc2[i][0], acc2[i][1], acc2[i][2], acc2[i][3] };
    f32x4 o1 = { acc2[i][4], acc2[i][5], acc2[i][6], acc2[i][7] };
    *(f32x4*)&Out[obase + (size_t)(s + i) * 1024 + e0]     = o0;
    *(f32x4*)&Out[obase + (size_t)(s + i) * 1024 + e0 + 4] = o1;
  }
}

extern "C" void kernel_launch(void* const* d_in, const int* in_sizes, int n_in,
                              void* d_out, int out_size, void* d_ws, size_t ws_size,
                              hipStream_t stream) {
  const float* x  = (const float*)d_in[0];
  const float* Wq = (const float*)d_in[1];
  const float* Wk = (const float*)d_in[2];
  const float* Wv = (const float*)d_in[3];
  const float* bq = (const float*)d_in[4];
  const float* bk = (const float*)d_in[5];
  const float* bv = (const float*)d_in[6];
  float* out = (float*)d_out;

  char* ws = (char*)d_ws;
  const size_t MiB = 1024ull * 1024ull;
  unsigned short* Xbf   = (unsigned short*)(ws);              //  8 MiB
  unsigned short* Wcat  = (unsigned short*)(ws + 8  * MiB);   //  6 MiB
  float*          Bcat  = (float*)         (ws + 14 * MiB);   // 12 KiB
  unsigned short* Qt    = (unsigned short*)(ws + 15 * MiB);   //  8 MiB
  unsigned short* Kt    = (unsigned short*)(ws + 23 * MiB);   //  8 MiB
  unsigned short* Vt    = (unsigned short*)(ws + 31 * MiB);   //  8 MiB
  float*          Mpart = (float*)         (ws + 39 * MiB);   //  4 MiB

  convert_pack<<<3586, 256, 0, stream>>>(x, Wq, Wk, Wv, bq, bk, bv,
                                         Xbf, Wcat, Bcat);
  qkv_gemm<<<256, 512, 0, stream>>>(Xbf, Wcat, Bcat, Qt, Kt, Vt);
  kv_outer<<<256, 64, 0, stream>>>(Kt, Vt, Mpart);
  qm_out<<<dim3(16, 16, 2), 256, 0, stream>>>(Qt, Mpart, out);
}

// Round 11
// 65.943 us; speedup vs baseline: 1.0689x; 1.0056x over previous
//
#include <hip/hip_runtime.h>

// B=2, S=2048, D_MODEL=1024, H=16, E=64.  Inputs/outputs FLOAT32.
// out = Q (norm * K^T V)  -- reassociated, no S x S scores.
// convert_pack -> qkv_gemm (256x192, K_STEP=64, k-half-sectioned double
// buffer, 4-phase counted-vmcnt pipeline, XOR chunk swizzle, wave-split
// staging, 2-D XCD CLUSTER mapping for L2 residency, transposed epilogue)
// -> kv_outer (MFMA) -> qm_out (fused reduce + Q.M).

typedef __attribute__((ext_vector_type(8))) __bf16 bf16x8;
typedef __attribute__((ext_vector_type(8))) short short8;
typedef __attribute__((ext_vector_type(4))) float f32x4;
typedef __attribute__((ext_vector_type(4))) unsigned short ushort4v;

#define NX  4194304   // 4096*1024
#define NW1 1048576   // 1024*1024
#define NW  3145728   // 3*NW1

__device__ __forceinline__ float bf2f(unsigned short u) {
  union { unsigned int i; float f; } v; v.i = ((unsigned int)u) << 16; return v.f;
}
__device__ __forceinline__ unsigned short f2bf(float f) {
  union { float f; unsigned int i; } v; v.f = f;
  unsigned int u = v.i;
  u += 0x7fffu + ((u >> 16) & 1u);   // RNE
  return (unsigned short)(u >> 16);
}

__device__ __forceinline__ void gload_lds16(const void* g, void* l) {
  __builtin_amdgcn_global_load_lds(
      (const __attribute__((address_space(1))) void*)(unsigned long long)(g),
      (__attribute__((address_space(3))) void*)(unsigned int)(unsigned long long)(l),
      16, 0, 0);
}

// ---------------------------------------------------------------------------
// Kernel 0: f32 -> bf16 convert/pack.
// ---------------------------------------------------------------------------
__global__ __launch_bounds__(256) void convert_pack(
    const float* __restrict__ x,
    const float* __restrict__ wq, const float* __restrict__ wk,
    const float* __restrict__ wv,
    const float* __restrict__ bq, const float* __restrict__ bk,
    const float* __restrict__ bv,
    unsigned short* __restrict__ Xbf, unsigned short* __restrict__ Wcat,
    float* __restrict__ Bcat)
{
  const long long t8 = ((long long)blockIdx.x * 256 + threadIdx.x) * 8;
  const float* src;
  unsigned short* dst;
  long long off;
  if (t8 < NX) {
    src = x; dst = Xbf; off = t8;
  } else if (t8 < NX + NW) {
    const long long w = t8 - NX;
    const int z = (int)(w >> 20);
    off = w & (NW1 - 1);
    src = (z == 0) ? wq : (z == 1) ? wk : wv;
    dst = Wcat + (long long)z * NW1;
  } else if (t8 < NX + NW + 3072) {
    const long long bo = t8 - (NX + NW);
    const int z = (int)(bo >> 10);
    const long long o2 = bo & 1023;
    const float* bsrc = (z == 0) ? bq : (z == 1) ? bk : bv;
    *(f32x4*)(Bcat + z * 1024 + o2)     = *(const f32x4*)(bsrc + o2);
    *(f32x4*)(Bcat + z * 1024 + o2 + 4) = *(const f32x4*)(bsrc + o2 + 4);
    return;
  } else {
    return;
  }
  f32x4 v0 = *(const f32x4*)(src + off);
  f32x4 v1 = *(const f32x4*)(src + off + 4);
  union { short8 s; unsigned short u[8]; } o;
#pragma unroll
  for (int j = 0; j < 4; ++j) {
    o.u[j]     = f2bf(v0[j]);
    o.u[4 + j] = f2bf(v1[j]);
  }
  *(short8*)(dst + off) = o.s;
}

// ---------------------------------------------------------------------------
// Kernel 1: C[r,c] = sum_d Xbf[r,d]*Wcat[c,d] + Bcat[c].
// R=4096, C=3072, K=1024.  BM=256 x BN=192, K_STEP=64, 8 waves (2M x 4N),
// grid 16x16 = 256 (1 block/CU).
// *** Round-11 change: 2-D XCD cluster mapping.  HW: xcd = blockIdx%8.
// XCD k owns a 4-rowTile x 8-colTile cluster (A 2 MiB + B 3 MiB ~= L2),
// traversed row-fastest (hot B panel 0.375 MiB, A streams).  Replaces the
// 1-D slab swizzle whose per-XCD B working set (6 MiB) thrashed L2 -> all
// B staging served by L3 (the suspected chip-level ~40 us limiter). ***
// Rest identical to round 10 (verified): k-half sections, wave-split
// staging, counted per-wave vmcnt, XOR chunk swizzle, transposed epilogue.
// ---------------------------------------------------------------------------
#define BUF_B 57344           // Ak0 16K + Ak1 16K + Bk0 12K + Bk1 12K
__global__ __launch_bounds__(512, 1) void qkv_gemm(
    const unsigned short* __restrict__ Xbf,
    const unsigned short* __restrict__ Wcat,
    const float* __restrict__ Bcat,
    unsigned short* __restrict__ Qt,
    unsigned short* __restrict__ Kt,
    unsigned short* __restrict__ Vt)
{
  __shared__ unsigned char lds[2 * BUF_B];   // 112 KB

  const int tid = threadIdx.x;
  // 2-D XCD cluster map (bijective: 8 xcd x 32 idx -> 16x16 tiles)
  const int xcd = blockIdx.x & 7;
  const int idx = blockIdx.x >> 3;          // 0..31
  const int rowTile = (xcd >> 1) * 4 + (idx & 3);
  const int colTile = (xcd & 1) * 8 + (idx >> 2);
  const int rowBase = rowTile * 256;
  const int colBase = colTile * 192;

  const int lane = tid & 63;
  const int wid  = tid >> 6;                // 0..7
  const int wr = (wid >> 2) * 128;          // 2 M-waves, 128 rows
  const int wc = (wid & 3) * 48;            // 4 N-waves, 48 cols
  const int lr = lane & 15;
  const int lk = lane >> 4;
  const int fofs = (lk ^ ((lr >> 1) & 3)) << 4;   // swizzled frag chunk
  const int frA = (wr + lr) * 64 + fofs;    // + m*1024
  const int frB = (wc + lr) * 64 + fofs;    // + n*1024

  const bool isA = (tid < 256);
  const int nl = isA ? 4 : 3;
  const int tloc = tid & 255;

  // staging: section unit u = l*256 + tloc; row = u>>2; chunk = u&3;
  // source chunk = (u&3) ^ ((row>>1)&3)  (inverse swizzle on global addr)
  const unsigned short* gp[4];
  int dofs[4];
#pragma unroll
  for (int l = 0; l < 4; ++l) {
    const int u = l * 256 + tloc;
    const int row = u >> 2;
    const int rowc = (!isA && row > 191) ? 0 : row;
    const int csrc = (u & 3) ^ ((rowc >> 1) & 3);
    gp[l] = isA ? (Xbf  + (size_t)(rowBase + rowc) * 1024 + csrc * 8)
                : (Wcat + (size_t)(colBase + rowc) * 1024 + csrc * 8);
    dofs[l] = u * 16;
  }

#define STGRP(secbase, kofs)                                 \
  { _Pragma("unroll") for (int l = 0; l < 4; ++l)            \
      if (l < nl) gload_lds16(gp[l] + (kofs), (secbase) + dofs[l]); }

  f32x4 acc[8][3] = {};

  // prologue: K-step 0, both k-halves.  A-waves: Ak0 then Ak1; B: Bk0, Bk1.
  if (isA) { STGRP(lds + 0,     0); STGRP(lds + 16384, 32); }
  else     { STGRP(lds + 32768, 0); STGRP(lds + 45056, 32); }

  for (int t = 0; t < 16; ++t) {
    const unsigned char* bufc = lds + (t & 1) * BUF_B;
    unsigned char* bufn = lds + ((t + 1) & 1) * BUF_B;
    const size_t kno = (size_t)(t + 1) * 64;
    const bool st = (t < 15);
    bf16x8 a[8], b0, b1, b2;

    // ---- P1: k-half 0, n0-1 ----
    if (isA) asm volatile("s_waitcnt vmcnt(4)" ::: "memory");
    else     asm volatile("s_waitcnt vmcnt(3)" ::: "memory");
    __builtin_amdgcn_s_barrier();
    {
      const unsigned char* As = bufc;           // Ak0
      const unsigned char* Bs = bufc + 32768;   // Bk0
#pragma unroll
      for (int m = 0; m < 8; ++m)
        a[m] = *(const bf16x8*)(As + frA + m * 1024);
      b0 = *(const bf16x8*)(Bs + frB);
      b1 = *(const bf16x8*)(Bs + frB + 1024);
      if (st && isA) STGRP(bufn + 0, kno);      // Ak0(t+1)
      __builtin_amdgcn_s_setprio(1);
#pragma unroll
      for (int m = 0; m < 8; ++m)
        acc[m][0] = __builtin_amdgcn_mfma_f32_16x16x32_bf16(a[m], b0, acc[m][0], 0, 0, 0);
#pragma unroll
      for (int m = 0; m < 8; ++m)
        acc[m][1] = __builtin_amdgcn_mfma_f32_16x16x32_bf16(a[m], b1, acc[m][1], 0, 0, 0);
      __builtin_amdgcn_s_setprio(0);
      // ---- P2: k-half 0, n2 ----
      b2 = *(const bf16x8*)(Bs + frB + 2048);
      if (st && !isA) STGRP(bufn + 32768, kno); // Bk0(t+1)
      __builtin_amdgcn_s_setprio(1);
#pragma unroll
      for (int m = 0; m < 8; ++m)
        acc[m][2] = __builtin_amdgcn_mfma_f32_16x16x32_bf16(a[m], b2, acc[m][2], 0, 0, 0);
      __builtin_amdgcn_s_setprio(0);
    }
    // ---- P3: k-half 1, n0-1 ----
    if (st) {
      if (isA) asm volatile("s_waitcnt vmcnt(4)" ::: "memory");
      else     asm volatile("s_waitcnt vmcnt(3)" ::: "memory");
    } else {
      asm volatile("s_waitcnt vmcnt(0)" ::: "memory");
    }
    __builtin_amdgcn_s_barrier();
    {
      const unsigned char* As = bufc + 16384;   // Ak1
      const unsigned char* Bs = bufc + 45056;   // Bk1
#pragma unroll
      for (int m = 0; m < 8; ++m)
        a[m] = *(const bf16x8*)(As + frA + m * 1024);
      b0 = *(const bf16x8*)(Bs + frB);
      b1 = *(const bf16x8*)(Bs + frB + 1024);
      if (st && isA) STGRP(bufn + 16384, kno + 32);   // Ak1(t+1)
      __builtin_amdgcn_s_setprio(1);
#pragma unroll
      for (int m = 0; m < 8; ++m)
        acc[m][0] = __builtin_amdgcn_mfma_f32_16x16x32_bf16(a[m], b0, acc[m][0], 0, 0, 0);
#pragma unroll
      for (int m = 0; m < 8; ++m)
        acc[m][1] = __builtin_amdgcn_mfma_f32_16x16x32_bf16(a[m], b1, acc[m][1], 0, 0, 0);
      __builtin_amdgcn_s_setprio(0);
      // ---- P4: k-half 1, n2 ----
      b2 = *(const bf16x8*)(Bs + frB + 2048);
      if (st && !isA) STGRP(bufn + 45056, kno + 32);  // Bk1(t+1)
      __builtin_amdgcn_s_setprio(1);
#pragma unroll
      for (int m = 0; m < 8; ++m)
        acc[m][2] = __builtin_amdgcn_mfma_f32_16x16x32_bf16(a[m], b2, acc[m][2], 0, 0, 0);
      __builtin_amdgcn_s_setprio(0);
    }
  }
#undef STGRP

  // Epilogue.  D mapping: col = lane&15 (lr), row = lk*4 + jj.
  const int bB = rowBase >> 11;             // batch
#pragma unroll
  for (int n = 0; n < 3; ++n) {
    const int colG = colBase + wc + n * 16 + lr;
    const float bval = Bcat[colG];
    const int zone = colG >> 10;            // uniform per 16-col fragment
    unsigned short* __restrict__ T = (zone == 0) ? Qt : (zone == 1) ? Kt : Vt;
    const int hf = (colG >> 6) & 15;
    const int f  = colG & 63;
    const size_t rowOff = ((size_t)(bB * 16 + hf) * 64 + f) * 2048;
#pragma unroll
    for (int m = 0; m < 8; ++m) {
      const int tpos = (rowBase + wr + m * 16 + lk * 4) & 2047;
      ushort4v pk;
#pragma unroll
      for (int jj = 0; jj < 4; ++jj)
        pk[jj] = f2bf(acc[m][n][jj] + bval);
      *(ushort4v*)&T[rowOff + tpos] = pk;
    }
  }
}

// ---------------------------------------------------------------------------
// Kernel 2 (MFMA): Mpart[blk][f][e] = sum_{t in chunk} Kt[bh][f][t]*Vt[bh][e][t]
// grid 256 blocks x 64 threads (1 wave).  blk = bh*8 + tchunk.
// ---------------------------------------------------------------------------
__global__ __launch_bounds__(64) void kv_outer(
    const unsigned short* __restrict__ Kt,
    const unsigned short* __restrict__ Vt,
    float* __restrict__ Mpart)
{
  const int lane = threadIdx.x;
  const int blk = blockIdx.x;
  const int bh = blk >> 3, tc = blk & 7;
  const int lr = lane & 15, lk = lane >> 4;
  const size_t base = (size_t)bh * 64 * 2048;

  f32x4 acc[4][4] = {};
#pragma unroll
  for (int ks = 0; ks < 8; ++ks) {
    const int t0 = tc * 256 + ks * 32 + lk * 8;
    bf16x8 af[4], bf[4];
#pragma unroll
    for (int m = 0; m < 4; ++m)
      af[m] = *(const bf16x8*)&Kt[base + (size_t)(m * 16 + lr) * 2048 + t0];
#pragma unroll
    for (int n = 0; n < 4; ++n)
      bf[n] = *(const bf16x8*)&Vt[base + (size_t)(n * 16 + lr) * 2048 + t0];
#pragma unroll
    for (int m = 0; m < 4; ++m)
#pragma unroll
      for (int n = 0; n < 4; ++n)
        acc[m][n] = __builtin_amdgcn_mfma_f32_16x16x32_bf16(af[m], bf[n], acc[m][n], 0, 0, 0);
  }
  float* out = Mpart + (size_t)blk * 4096;
#pragma unroll
  for (int m = 0; m < 4; ++m)
#pragma unroll
    for (int n = 0; n < 4; ++n)
#pragma unroll
      for (int j = 0; j < 4; ++j)
        out[(m * 16 + lk * 4 + j) * 64 + n * 16 + lr] = acc[m][n][j];
}

// ---------------------------------------------------------------------------
// Kernel 3: Out[s, h*64+e] = sum_f Qt[bh][f][s] * (norm * sum_ch Mpart)[f][e]
// Fused 8-partial reduce + Q.M.  grid (16 s-chunks, 16 h, 2 b), 256 thr.
// ---------------------------------------------------------------------------
__global__ __launch_bounds__(256) void qm_out(
    const unsigned short* __restrict__ Qt, const float* __restrict__ Mpart,
    float* __restrict__ Out)
{
  __shared__ float Ms[64 * 64];      // 16 KB
  __shared__ float Qst[64 * 132];    // [f][s] padded
  const int tid = threadIdx.x;
  const int b = blockIdx.z, h = blockIdx.y, s0 = blockIdx.x * 128;
  const int bh = b * 16 + h;

#pragma unroll
  for (int i = 0; i < 4; ++i) {
    const int off = i * 1024 + tid * 4;
    f32x4 s = {};
#pragma unroll
    for (int ch = 0; ch < 8; ++ch)
      s += *(const f32x4*)&Mpart[((size_t)bh * 8 + ch) * 4096 + off];
    s *= 0.125f;   // 64^-0.5
    *(f32x4*)&Ms[off] = s;
  }
  const size_t qbase = (size_t)bh * 64 * 2048;
#pragma unroll
  for (int i = 0; i < 4; ++i) {
    const int slot = i * 256 + tid;          // 0..1023
    const int f = slot >> 4, c = slot & 15;
    short8 q = *(const short8*)&Qt[qbase + (size_t)f * 2048 + s0 + c * 8];
#pragma unroll
    for (int j = 0; j < 8; ++j)
      Qst[f * 132 + c * 8 + j] = bf2f((unsigned short)q[j]);
  }
  __syncthreads();

  const int s = (tid >> 3) * 4;       // 4 rows / thread
  const int e0 = (tid & 7) * 8;       // 8 cols / thread
  float acc2[4][8] = {};
  for (int f = 0; f < 64; ++f) {
    f32x4 m0 = *(const f32x4*)&Ms[f * 64 + e0];
    f32x4 m1 = *(const f32x4*)&Ms[f * 64 + e0 + 4];
#pragma unroll
    for (int i = 0; i < 4; ++i) {
      const float q = Qst[f * 132 + s + i];
#pragma unroll
      for (int j = 0; j < 4; ++j) {
        acc2[i][j]     += q * m0[j];
        acc2[i][j + 4] += q * m1[j];
      }
    }
  }
  const size_t obase = ((size_t)b * 2048 + s0) * 1024 + h * 64;
#pragma unroll
  for (int i = 0; i < 4; ++i) {
    f32x4 o0 = { acc2[i][0], acc2[i][1], acc2[i][2], acc2[i][3] };
    f32x4 o1 = { acc2[i][4], acc2[i][5], acc2[i][6], acc2[i][7] };
    *(f32x4*)&Out[obase + (size_t)(s + i) * 1024 + e0]     = o0;
    *(f32x4*)&Out[obase + (size_t)(s + i) * 1024 + e0 + 4] = o1;
  }
}

extern "C" void kernel_launch(void* const* d_in, const int* in_sizes, int n_in,
                              void* d_out, int out_size, void* d_ws, size_t ws_size,
                              hipStream_t stream) {
  const float* x  = (const float*)d_in[0];
  const float* Wq = (const float*)d_in[1];
  const float* Wk = (const float*)d_in[2];
  const float* Wv = (const float*)d_in[3];
  const float* bq = (const float*)d_in[4];
  const float* bk = (const float*)d_in[5];
  const float* bv = (const float*)d_in[6];
  float* out = (float*)d_out;

  char* ws = (char*)d_ws;
  const size_t MiB = 1024ull * 1024ull;
  unsigned short* Xbf   = (unsigned short*)(ws);              //  8 MiB
  unsigned short* Wcat  = (unsigned short*)(ws + 8  * MiB);   //  6 MiB
  float*          Bcat  = (float*)         (ws + 14 * MiB);   // 12 KiB
  unsigned short* Qt    = (unsigned short*)(ws + 15 * MiB);   //  8 MiB
  unsigned short* Kt    = (unsigned short*)(ws + 23 * MiB);   //  8 MiB
  unsigned short* Vt    = (unsigned short*)(ws + 31 * MiB);   //  8 MiB
  float*          Mpart = (float*)         (ws + 39 * MiB);   //  4 MiB

  convert_pack<<<3586, 256, 0, stream>>>(x, Wq, Wk, Wv, bq, bk, bv,
                                         Xbf, Wcat, Bcat);
  qkv_gemm<<<256, 512, 0, stream>>>(Xbf, Wcat, Bcat, Qt, Kt, Vt);
  kv_outer<<<256, 64, 0, stream>>>(Kt, Vt, Mpart);
  qm_out<<<dim3(16, 16, 2), 256, 0, stream>>>(Qt, Mpart, out);
}